// Round 1
// baseline (785.032 us; speedup 1.0000x reference)
//
#include <hip/hip_runtime.h>
#include <math.h>

#define NN 100000
#define EE 1600000
#define GG 512
#define INF_ 128
#define HID 64
#define EPS 1e-5f

#define SCAN_CHUNK 1024
#define NB 98   // ceil(NN/SCAN_CHUNK)

// ---------------- CSR build ----------------

__global__ void k_hist(const int* __restrict__ ei, int* __restrict__ cnt) {
    int e = blockIdx.x * 256 + threadIdx.x;
    if (e < EE) atomicAdd(&cnt[ei[EE + e]], 1);
}

// per-block reduce of cnt (1024 elems/block) -> bsum; also dinv = rsqrt(1+cnt)
__global__ void k_block_reduce(const int* __restrict__ cnt, int* __restrict__ bsum,
                               float* __restrict__ dinv) {
    int b = blockIdx.x, t = threadIdx.x;
    int i = b * SCAN_CHUNK + t * 4;
    int c0 = (i     < NN) ? cnt[i]     : 0;
    int c1 = (i + 1 < NN) ? cnt[i + 1] : 0;
    int c2 = (i + 2 < NN) ? cnt[i + 2] : 0;
    int c3 = (i + 3 < NN) ? cnt[i + 3] : 0;
    if (i     < NN) dinv[i]     = rsqrtf(1.f + (float)c0);
    if (i + 1 < NN) dinv[i + 1] = rsqrtf(1.f + (float)c1);
    if (i + 2 < NN) dinv[i + 2] = rsqrtf(1.f + (float)c2);
    if (i + 3 < NN) dinv[i + 3] = rsqrtf(1.f + (float)c3);
    int v = c0 + c1 + c2 + c3;
    for (int d = 32; d > 0; d >>= 1) v += __shfl_down(v, d);
    __shared__ int ws4[4];
    int lane = t & 63, w = t >> 6;
    if (lane == 0) ws4[w] = v;
    __syncthreads();
    if (t == 0) bsum[b] = ws4[0] + ws4[1] + ws4[2] + ws4[3];
}

__global__ void k_scan_bsums(int* __restrict__ bsum, int* __restrict__ offs) {
    __shared__ int tmp[128];
    int t = threadIdx.x;
    for (int i = t; i < NB; i += 128) tmp[i] = bsum[i];
    __syncthreads();
    if (t == 0) {
        int run = 0;
        for (int i = 0; i < NB; ++i) { int v = tmp[i]; tmp[i] = run; run += v; }
        offs[NN] = run;  // == EE
    }
    __syncthreads();
    for (int i = t; i < NB; i += 128) bsum[i] = tmp[i];
}

__global__ void k_scan_apply(const int* __restrict__ cnt, const int* __restrict__ bsum,
                             int* __restrict__ offs, int* __restrict__ cursor) {
    int b = blockIdx.x, t = threadIdx.x;
    int i = b * SCAN_CHUNK + t * 4;
    int c0 = (i     < NN) ? cnt[i]     : 0;
    int c1 = (i + 1 < NN) ? cnt[i + 1] : 0;
    int c2 = (i + 2 < NN) ? cnt[i + 2] : 0;
    int c3 = (i + 3 < NN) ? cnt[i + 3] : 0;
    int s = c0 + c1 + c2 + c3;
    int lane = t & 63, w = t >> 6;
    int v = s;
    for (int d = 1; d < 64; d <<= 1) { int n = __shfl_up(v, d); if (lane >= d) v += n; }
    __shared__ int wsum[4];
    if (lane == 63) wsum[w] = v;
    __syncthreads();
    int wbase = 0;
    for (int q = 0; q < w; ++q) wbase += wsum[q];
    int o0 = bsum[b] + wbase + (v - s);
    int o1 = o0 + c0, o2 = o1 + c1, o3 = o2 + c2;
    if (i     < NN) { offs[i]     = o0; cursor[i]     = o0; }
    if (i + 1 < NN) { offs[i + 1] = o1; cursor[i + 1] = o1; }
    if (i + 2 < NN) { offs[i + 2] = o2; cursor[i + 2] = o2; }
    if (i + 3 < NN) { offs[i + 3] = o3; cursor[i + 3] = o3; }
}

__global__ void k_scatter(const int* __restrict__ ei, int* __restrict__ cursor,
                          const float* __restrict__ dinv, int* __restrict__ col,
                          float* __restrict__ wgt) {
    int e = blockIdx.x * 256 + threadIdx.x;
    if (e >= EE) return;
    int s = ei[e], d = ei[EE + e];
    int p = atomicAdd(&cursor[d], 1);
    col[p] = s;
    wgt[p] = dinv[s];
}

// ---------------- BN constant folding ----------------
// u = agg_norm + self + b ; bn(u) = u*sc + (b - rm)*sc + be
__global__ void k_precompute_bn(const float* b1, const float* g1, const float* be1,
                                const float* rm1, const float* rv1,
                                const float* b2, const float* g2, const float* be2,
                                const float* rm2, const float* rv2, float* sc) {
    int l = threadIdx.x;
    float s1 = g1[l] * rsqrtf(rv1[l] + EPS);
    sc[l]       = s1;
    sc[64 + l]  = (b1[l] - rm1[l]) * s1 + be1[l];
    float s2 = g2[l] * rsqrtf(rv2[l] + EPS);
    sc[128 + l] = s2;
    sc[192 + l] = (b2[l] - rm2[l]) * s2 + be2[l];
}

// ---------------- GEMM: [nrows, K] @ [K, 64] ----------------
template <int K>
__global__ void k_gemm_rows(const float* __restrict__ X, const float* __restrict__ W,
                            float* __restrict__ out, int nrows) {
    __shared__ float Wl[K * 64];
    int tid = threadIdx.x;  // 256
    for (int i = tid * 4; i < K * 64; i += 1024)
        *(float4*)&Wl[i] = *(const float4*)&W[i];
    __syncthreads();
    int lane = tid & 63, wv = tid >> 6;
    int r0 = blockIdx.x * 64 + wv * 16;
    for (int rr = 0; rr < 16; ++rr) {
        int r = r0 + rr;
        if (r >= nrows) return;   // r is wave-uniform
        const float* xr = X + (long)r * K;
        float acc = 0.f;
#pragma unroll
        for (int k = 0; k < K; k += 4) {
            float4 xv = *(const float4*)(xr + k);
            acc = fmaf(xv.x, Wl[(k + 0) * 64 + lane], acc);
            acc = fmaf(xv.y, Wl[(k + 1) * 64 + lane], acc);
            acc = fmaf(xv.z, Wl[(k + 2) * 64 + lane], acc);
            acc = fmaf(xv.w, Wl[(k + 3) * 64 + lane], acc);
        }
        out[(long)r * 64 + lane] = acc;
    }
}

// ---------------- fused GCN aggregate + selfloop + BN + ReLU (+resid) ------
// one wave per node; lane = feature
__global__ void k_gcn_gather(const float* __restrict__ hw, const int* __restrict__ col,
                             const int* __restrict__ offs, const float* __restrict__ wgt,
                             const float* __restrict__ dinv, const float* __restrict__ scale,
                             const float* __restrict__ shift, const float* __restrict__ resid,
                             float* __restrict__ out) {
    int node = blockIdx.x * 4 + (threadIdx.x >> 6);
    if (node >= NN) return;
    int lane = threadIdx.x & 63;
    int e0 = offs[node], e1 = offs[node + 1];
    float di = dinv[node];
    float a0 = 0.f, a1 = 0.f, a2 = 0.f, a3 = 0.f;
    for (int base = e0; base < e1; base += 64) {
        int m = e1 - base; if (m > 64) m = 64;
        int srcv = 0; float wv = 0.f;
        if (lane < m) { srcv = col[base + lane]; wv = wgt[base + lane]; }
        int j = 0;
        for (; j + 4 <= m; j += 4) {
            int s0 = __shfl(srcv, j), s1 = __shfl(srcv, j + 1);
            int s2 = __shfl(srcv, j + 2), s3 = __shfl(srcv, j + 3);
            float n0 = __shfl(wv, j), n1 = __shfl(wv, j + 1);
            float n2 = __shfl(wv, j + 2), n3 = __shfl(wv, j + 3);
            float v0 = hw[s0 * 64 + lane];
            float v1 = hw[s1 * 64 + lane];
            float v2 = hw[s2 * 64 + lane];
            float v3 = hw[s3 * 64 + lane];
            a0 = fmaf(v0, n0, a0); a1 = fmaf(v1, n1, a1);
            a2 = fmaf(v2, n2, a2); a3 = fmaf(v3, n3, a3);
        }
        for (; j < m; ++j) {
            int s = __shfl(srcv, j); float n = __shfl(wv, j);
            a0 = fmaf(hw[s * 64 + lane], n, a0);
        }
    }
    float acc = ((a0 + a1) + (a2 + a3)) * di;          // edge sum * dinv[dst]
    float v = acc + hw[(long)node * 64 + lane] * di * di;  // self-loop
    v = fmaf(v, scale[lane], shift[lane]);             // folded bias + BN
    v = fmaxf(v, 0.f);                                 // ReLU
    if (resid) v += resid[(long)node * 64 + lane];
    out[(long)node * 64 + lane] = v;
}

// ---------------- pooling over sorted batch ----------------
__global__ void k_pool(const float* __restrict__ h, const int* __restrict__ batch,
                       float* __restrict__ msum, float* __restrict__ mmax,
                       float* __restrict__ gcnt) {
    int lane = threadIdx.x;  // 64
    int i0 = blockIdx.x * 128;
    int i1 = i0 + 128; if (i1 > NN) i1 = NN;
    int cur = batch[i0];
    float sum = 0.f, mx = 0.f; int c = 0;
    for (int i = i0; i < i1; ++i) {
        int g = batch[i];
        if (g != cur) {
            atomicAdd(&msum[cur * 64 + lane], sum);
            atomicMax((unsigned int*)&mmax[cur * 64 + lane], __float_as_uint(mx));
            if (lane == 0) atomicAdd(&gcnt[cur], (float)c);
            sum = 0.f; mx = 0.f; c = 0; cur = g;
        }
        float v = h[(long)i * 64 + lane];
        sum += v; mx = fmaxf(mx, v); ++c;
    }
    atomicAdd(&msum[cur * 64 + lane], sum);
    atomicMax((unsigned int*)&mmax[cur * 64 + lane], __float_as_uint(mx));
    if (lane == 0) atomicAdd(&gcnt[cur], (float)c);
}

// ---------------- MLP head, one block per graph ----------------
__global__ void k_head(const float* __restrict__ msum, const float* __restrict__ mmax,
                       const float* __restrict__ gcnt,
                       const float* __restrict__ Wh1, const float* __restrict__ bh1,
                       const float* __restrict__ Wh2, const float* __restrict__ bh2,
                       const float* __restrict__ Wh3, const float* __restrict__ bh3,
                       float* __restrict__ out) {
    int g = blockIdx.x, t = threadIdx.x;  // 64 threads
    __shared__ float hg[128];
    __shared__ float z1[64];
    __shared__ float z2[32];
    float c = fmaxf(gcnt[g], 1.f);
    hg[t]      = msum[g * 64 + t] / c;
    hg[64 + t] = mmax[g * 64 + t];
    __syncthreads();
    float acc = bh1[t];
#pragma unroll 8
    for (int k = 0; k < 128; ++k) acc = fmaf(hg[k], Wh1[k * 64 + t], acc);
    z1[t] = fmaxf(acc, 0.f);
    __syncthreads();
    if (t < 32) {
        float a2 = bh2[t];
#pragma unroll 8
        for (int k = 0; k < 64; ++k) a2 = fmaf(z1[k], Wh2[k * 32 + t], a2);
        z2[t] = fmaxf(a2, 0.f);
    }
    __syncthreads();
    if (t == 0) {
        float a3 = bh3[0];
        for (int k = 0; k < 32; ++k) a3 = fmaf(z2[k], Wh3[k], a3);
        out[g] = 1.f / (1.f + expf(-a3));
    }
}

// ---------------- launcher ----------------

static inline size_t alignup(size_t x) { return (x + 255) & ~(size_t)255; }

extern "C" void kernel_launch(void* const* d_in, const int* in_sizes, int n_in,
                              void* d_out, int out_size, void* d_ws, size_t ws_size,
                              hipStream_t stream) {
    const float* x   = (const float*)d_in[0];
    const int*   ei  = (const int*)d_in[1];
    const int*   bat = (const int*)d_in[2];
    const float* W1  = (const float*)d_in[3];
    const float* b1  = (const float*)d_in[4];
    const float* g1  = (const float*)d_in[5];
    const float* be1 = (const float*)d_in[6];
    const float* rm1 = (const float*)d_in[7];
    const float* rv1 = (const float*)d_in[8];
    const float* W2  = (const float*)d_in[9];
    const float* b2  = (const float*)d_in[10];
    const float* g2  = (const float*)d_in[11];
    const float* be2 = (const float*)d_in[12];
    const float* rm2 = (const float*)d_in[13];
    const float* rv2 = (const float*)d_in[14];
    const float* Wh1 = (const float*)d_in[15];
    const float* bh1 = (const float*)d_in[16];
    const float* Wh2 = (const float*)d_in[17];
    const float* bh2 = (const float*)d_in[18];
    const float* Wh3 = (const float*)d_in[19];
    const float* bh3 = (const float*)d_in[20];
    float* out = (float*)d_out;

    char* ws = (char*)d_ws;
    size_t o = 0;
    int*   cnt    = (int*)(ws + o);  o = alignup(o + (NN + 1) * 4);
    int*   offs   = (int*)(ws + o);  o = alignup(o + (NN + 1) * 4);
    int*   cursor = (int*)(ws + o);  o = alignup(o + (size_t)NN * 4);
    int*   col    = (int*)(ws + o);  o = alignup(o + (size_t)EE * 4);
    float* wgt    = (float*)(ws + o); o = alignup(o + (size_t)EE * 4);
    float* dinv   = (float*)(ws + o); o = alignup(o + (size_t)NN * 4);
    int*   bsum   = (int*)(ws + o);  o = alignup(o + 1024);
    float* scb    = (float*)(ws + o); o = alignup(o + 4 * 64 * 4);
    float* msum   = (float*)(ws + o);                       // pool region start
    size_t pool_off = o;              o += (size_t)GG * 64 * 4;
    float* mmax   = (float*)(ws + o); o += (size_t)GG * 64 * 4;
    float* gcnt   = (float*)(ws + o); o += (size_t)GG * 4;
    size_t pool_bytes = o - pool_off; o = alignup(o);
    float* hw     = (float*)(ws + o); o = alignup(o + (size_t)NN * 64 * 4);
    float* h      = (float*)(ws + o); o = alignup(o + (size_t)NN * 64 * 4);
    (void)ws_size; (void)n_in; (void)in_sizes; (void)out_size;

    hipMemsetAsync(cnt, 0, (size_t)NN * 4, stream);
    hipMemsetAsync(ws + pool_off, 0, pool_bytes, stream);

    k_precompute_bn<<<1, 64, 0, stream>>>(b1, g1, be1, rm1, rv1, b2, g2, be2, rm2, rv2, scb);
    k_hist<<<EE / 256, 256, 0, stream>>>(ei, cnt);
    k_block_reduce<<<NB, 256, 0, stream>>>(cnt, bsum, dinv);
    k_scan_bsums<<<1, 128, 0, stream>>>(bsum, offs);
    k_scan_apply<<<NB, 256, 0, stream>>>(cnt, bsum, offs, cursor);
    k_scatter<<<EE / 256, 256, 0, stream>>>(ei, cursor, dinv, col, wgt);

    // layer 1
    k_gemm_rows<INF_><<<(NN + 63) / 64, 256, 0, stream>>>(x, W1, hw, NN);
    k_gcn_gather<<<(NN + 3) / 4, 256, 0, stream>>>(hw, col, offs, wgt, dinv,
                                                   scb, scb + 64, nullptr, h);
    // layer 2 (residual, in-place into h)
    k_gemm_rows<HID><<<(NN + 63) / 64, 256, 0, stream>>>(h, W2, hw, NN);
    k_gcn_gather<<<(NN + 3) / 4, 256, 0, stream>>>(hw, col, offs, wgt, dinv,
                                                   scb + 128, scb + 192, h, h);
    // pooling + head
    k_pool<<<(NN + 127) / 128, 64, 0, stream>>>(h, bat, msum, mmax, gcnt);
    k_head<<<GG, 64, 0, stream>>>(msum, mmax, gcnt, Wh1, bh1, Wh2, bh2, Wh3, bh3, out);
}